// Round 15
// baseline (136.438 us; speedup 1.0000x reference)
//
#include <hip/hip_runtime.h>
#include <hip/hip_bf16.h>
#include <hip/hip_fp16.h>

typedef unsigned short u16;
typedef unsigned int u32;
typedef __attribute__((ext_vector_type(4))) short short4v;  // mfma 16x16x16 A/B frag (2 VGPRs)
typedef __attribute__((ext_vector_type(4))) float f32x4;    // mfma C/D frag
typedef __attribute__((ext_vector_type(2))) _Float16 half2v; // packed fp16 pair

#define NN 30
#define FF 4
#define EE 870
#define BSZ 32
#define CC 64
#define TT 128
#define NF 120
#define TSTRIDE 15240
#define OUTHALF 487680
#define AST 68            // S row stride (u16); 17-dw stride -> 2-way max on frag reads (free)
#define WST 68            // LDS weight row stride (u16)
#define NSETS 4           // channel-sets per block (share one weight copy)
#define NCPB 2            // channels per set (amortize staging; processed SERIALLY)
#define BPB  8            // blocks per bs -> grid 256 = 1 block/CU

// R15 = R14 resubmitted verbatim (R14 bench was an infra failure - container
// died twice; the kernel never ran). Theory unchanged:
// R12 staging (T14 reverted: staging is NOT load-latency bound) + ROW-PAIR
// edge loop. The step loop is stall-bound (VALUBusy 48% @ 4 waves/SIMD): the
// edge m-loop is an 8-deep sequential fdot2 chain per accumulator. Rows are
// independent and share pJp -> process rows (i, i+4) per iteration:
// 4 independent chains + 2 add/max streams, ~2x ILP, +~12 VGPR only.
// Per-row accumulation order unchanged -> bit-identical numerics.
// unroll-1 guards the pair loop (R10/R11: compiler unroll inflates live
// set past the cap and spills wholesale).
// Channel-split (R9-R11) permanently abandoned (3x compiler spills).

__device__ __forceinline__ float bf2f(u16 u) {
    union { u32 i; float f; } v; v.i = ((u32)u) << 16; return v.f;
}
// fast RNE f32->bf16 (finite values): ~4 VALU instead of libcall sequence
__device__ __forceinline__ u16 f2bf_fast(float f) {
    union { float f; u32 u; } v; v.f = f;
    return (u16)((v.u + 0x7FFFu + ((v.u >> 16) & 1u)) >> 16);
}
__device__ __forceinline__ float ldv(const void* p, int idx, int isbf) {
    if (isbf) return bf2f(((const u16*)p)[idx]);
    return ((const float*)p)[idx];
}
// fast softplus+clip: v_exp/v_log based. Matches exact path at both clip
// boundaries (large +z: log(1+0)=0; very -z: underflows to 0 then clips to 1e-8).
__device__ __forceinline__ float softplus_clip(float z) {
    float t = __expf(-fabsf(z));
    float sp = fmaxf(z, 0.f) + __logf(1.f + t);
    return fminf(fmaxf(sp, 1e-8f), 100.f);
}
__device__ __forceinline__ f32x4 MFMA16(short4v a, short4v b, f32x4 c) {
    return __builtin_amdgcn_mfma_f32_16x16x16bf16_1k(a, b, c, 0, 0, 0);
}

__device__ __forceinline__ int probe_isbf(const u16* g, int lane) {
    int hit = (g[2 * lane] == 0x3F80u) | (g[128 + 2 * lane] == 0x3F80u);
    unsigned long long b = __ballot(hit);
    return (b != 0ull) ? 1 : 0;
}

// LDS = 43520(W) + 4*4352(S) + 8*480(xN) + 128 gmask + 1280 bias = 66176 B.
// launch_bounds(1024, 4): VGPR cap 128; ~64-80 VGPR expected.
// Spill tripwire: FETCH/WRITE must stay ~1.45/3.81 MB.
// NOTE: (1024, 8) regressed badly: 64-VGPR cap forced scratch spill. Keep 4.
__global__ __launch_bounds__(1024, 4)
void sim_fused(const void* __restrict__ data,
               const void* __restrict__ graph,
               const void* __restrict__ mW1, const void* __restrict__ mB1,
               const void* __restrict__ mW2, const void* __restrict__ mB2,
               const void* __restrict__ aW1, const void* __restrict__ aB1,
               const void* __restrict__ aW2, const void* __restrict__ aB2,
               const void* __restrict__ aW3, const void* __restrict__ aB3,
               const void* __restrict__ vW1, const void* __restrict__ vB1,
               const void* __restrict__ vW2, const void* __restrict__ vB2,
               const void* __restrict__ vW3, const void* __restrict__ vB3,
               void* __restrict__ out)
{
    __shared__ __align__(16) float xN[NSETS][NCPB][NF];
    __shared__ __align__(16) u32 gmaskS[32];
    __shared__ __align__(16) u16 S[NSETS][32 * AST];
    __shared__ __align__(16) u16 lwM2[64 * WST];
    __shared__ __align__(16) u16 lwH1m[64 * WST];
    __shared__ __align__(16) u16 lwH2m[64 * WST];
    __shared__ __align__(16) u16 lwH1v[64 * WST];
    __shared__ __align__(16) u16 lwH2v[64 * WST];
    __shared__ __align__(16) float biasL[5 * 64];  // mB2|aB1|aB2|vB1|vB2

    const int tid  = threadIdx.x;
    const int lane = tid & 63;
    const int wv   = tid >> 6;        // 0..15
    const int set  = wv >> 2;         // 0..3 : channel-set
    const int swv  = wv & 3;          // 0..3 within set
    const int ln15 = lane & 15;
    const int quad = lane >> 4;
    const int bs   = blockIdx.x / BPB;
    const int bg   = blockIdx.x % BPB;
    const int cg   = bg * NSETS + set; // channel group 0..31 (NCPB channels each)
    const int isbf = probe_isbf((const u16*)graph, lane);

    const bool isMean = (swv < 2);
    const int nb = swv & 1;           // this wave's 16-node block

    // ---- phase 0: zero gmask + S pad rows ----
    if (tid < 32) gmaskS[tid] = 0u;
    if (tid < 512) {  // zero pad rows 30,31 of all 4 sets' S (stay zero forever)
        int s2 = tid >> 7, row = 30 + ((tid >> 6) & 1);
        S[s2][row * AST + (tid & 63)] = 0;
    }
    __syncthreads();   // gmask zeroing visible before atomics

    // ---- phase 1: one-time staging (masks, weights transposed, biases, xN) ----
    if (tid < EE) {    // coalesced: graph row for this bs is contiguous
        int i = tid / 29;
        int e = tid - i * 29;
        if (ldv(graph, bs * EE + tid, isbf) > 0.5f)
            atomicOr(&gmaskS[i], 1u << e);
    }
    // transpose five 64x64 weights into LDS o-major rows (stride WST).
    if (isbf) {
        // bf16 source: u32 loads (2 o's per load), raw u16 writes
        // (f2bf(bf2f(x)) is identity -> numerics unchanged vs scalar path)
        for (int idx2 = tid; idx2 < 2048; idx2 += 1024) {  // 2 iters x 5 arrays
            int k = idx2 >> 5, o = (idx2 & 31) * 2;
            int d0 = o * WST + k, d1 = d0 + WST;
            u32 w;
            w = ((const u32*)mW2)[idx2]; lwM2[d0]  = (u16)w; lwM2[d1]  = (u16)(w >> 16);
            w = ((const u32*)aW1)[idx2]; lwH1m[d0] = (u16)w; lwH1m[d1] = (u16)(w >> 16);
            w = ((const u32*)aW2)[idx2]; lwH2m[d0] = (u16)w; lwH2m[d1] = (u16)(w >> 16);
            w = ((const u32*)vW1)[idx2]; lwH1v[d0] = (u16)w; lwH1v[d1] = (u16)(w >> 16);
            w = ((const u32*)vW2)[idx2]; lwH2v[d0] = (u16)w; lwH2v[d1] = (u16)(w >> 16);
        }
    } else {
        for (int idx = tid; idx < 4096; idx += 1024) {  // 4 iters x 5 arrays
            int k = idx >> 6, o = idx & 63;
            int d = o * WST + k;
            lwM2[d]  = f2bf_fast(((const float*)mW2)[idx]);
            lwH1m[d] = f2bf_fast(((const float*)aW1)[idx]);
            lwH2m[d] = f2bf_fast(((const float*)aW2)[idx]);
            lwH1v[d] = f2bf_fast(((const float*)vW1)[idx]);
            lwH2v[d] = f2bf_fast(((const float*)vW2)[idx]);
        }
    }
    if (tid < 64) {
        biasL[tid]       = ldv(mB2, tid, isbf);
        biasL[64 + tid]  = ldv(aB1, tid, isbf);
        biasL[128 + tid] = ldv(aB2, tid, isbf);
        biasL[192 + tid] = ldv(vB1, tid, isbf);
        biasL[256 + tid] = ldv(vB2, tid, isbf);
    }
    // stage BOTH channels' features for this set (upfront: saves 2 barriers)
    {
        const int setTid = tid & 255;
#pragma unroll
        for (int cj = 0; cj < NCPB; cj++) {
            const int cc = cg * NCPB + cj;
            if (isbf) {
                if (setTid < 60) {
                    u32 w = ((const u32*)data)[((bs * TT + 2 * cc) * NF) / 2 + setTid];
                    xN[set][cj][setTid * 2]     = bf2f((u16)(w & 0xFFFF));
                    xN[set][cj][setTid * 2 + 1] = bf2f((u16)(w >> 16));
                }
            } else {
                if (setTid < NF)
                    xN[set][cj][setTid] = ((const float*)data)[(bs * TT + 2 * cc) * NF + setTid];
            }
        }
    }

    // ---- register-resident constants (no LDS dependency) ----
    float w1r[8];
#pragma unroll
    for (int k = 0; k < 8; k++) w1r[k] = ldv(mW1, k * 64 + lane, isbf);
    const float b1r = ldv(mB1, lane, isbf);
    float b3r[4];
#pragma unroll
    for (int r = 0; r < 4; r++) b3r[r] = ldv(isMean ? aB3 : vB3, r, isbf);

    const u16* wH1 = isMean ? lwH1m : lwH1v;
    const u16* wH2 = isMean ? lwH2m : lwH2v;
    const float* bAgg = biasL;
    const float* bH1  = isMean ? (biasL + 64)  : (biasL + 192);
    const float* bH2  = isMean ? (biasL + 128) : (biasL + 256);

    // W3^T A-fragments in registers (16x64 padded; rows>=4 zero)
    const void* W3src = isMean ? aW3 : vW3;
    short4v eA[4];
#pragma unroll
    for (int kb = 0; kb < 4; kb++) {
        union { short4v v; u16 s[4]; } pk;
#pragma unroll
        for (int j = 0; j < 4; j++) {
            int k = kb * 16 + quad * 4 + j;
            pk.s[j] = (ln15 < 4)
                ? (isbf ? ((const u16*)W3src)[k * 4 + ln15]
                        : f2bf_fast(((const float*)W3src)[k * 4 + ln15]))
                : (u16)0;
        }
        eA[kb] = pk.v;
    }

    __syncthreads();   // one-time staging visible

    const int myNode = nb * 16 + ln15;
    const float ngp = (myNode < NN) ? (float)__popc(gmaskS[myNode]) : 0.f;

    // transposed-chain layer: register B-frag in, register B-frag out
    auto runLayer = [&](const u16* wl, const float* bl, const short4v* Bin,
                        short4v* Bout, float bscale, bool doRelu) {
#pragma unroll
        for (int fb = 0; fb < 4; fb++) {
            f32x4 acc = {0.f, 0.f, 0.f, 0.f};
#pragma unroll
            for (int kb = 0; kb < 4; kb++) {
                short4v a = *(const short4v*)&wl[(fb * 16 + ln15) * WST + kb * 16 + quad * 4];
                acc = MFMA16(a, Bin[kb], acc);
            }
            float4 bv = *(const float4*)&bl[fb * 16 + quad * 4];
            union { short4v v; u16 s[4]; } pk;
#pragma unroll
            for (int r = 0; r < 4; r++) {
                float val = acc[r] + bscale * (&bv.x)[r];
                if (doRelu) val = fmaxf(val, 0.f);
                pk.s[r] = f2bf_fast(val);
            }
            Bout[fb] = pk.v;
        }
    };

    const half2v zero2 = {(_Float16)0.f, (_Float16)0.f};

    for (int ci = 0; ci < NCPB; ci++) {
        const int c = cg * NCPB + ci;

        for (int step = 0; step < 2; step++) {
            // ---- pJ pairs in registers (per-wave redundant; no LDS, no barrier) ----
            // pJp[m] = fp16x2 { x_{2m}.W1[4:8,lane], x_{2m+1}.W1[4:8,lane] }, RNE
            half2v pJp[15];
#pragma unroll
            for (int m = 0; m < 15; m++) {
                float4 xa = *(const float4*)&xN[set][ci][(2 * m) * 4];
                float4 xb = *(const float4*)&xN[set][ci][(2 * m + 1) * 4];
                half2v p;
                p.x = (_Float16)(xa.x * w1r[4] + xa.y * w1r[5] + xa.z * w1r[6] + xa.w * w1r[7]);
                p.y = (_Float16)(xb.x * w1r[4] + xb.y * w1r[5] + xb.z * w1r[6] + xb.w * w1r[7]);
                pJp[m] = p;
            }

            // ---- edge accumulation, ROW-PAIRED: rows (i, i+4) share pJp ----
            // 4 independent fdot2 chains + 2 add/max streams per iteration.
            // Per-row chain order identical to R12 -> bit-identical numerics.
            int i = swv;
#pragma unroll 1
            for (; i + 4 < NN; i += 8) {
                const int iB = i + 4;
                float4 xvA = *(const float4*)&xN[set][ci][i * 4];
                float4 xvB = *(const float4*)&xN[set][ci][iB * 4];
                float pIA = b1r + xvA.x * w1r[0] + xvA.y * w1r[1] + xvA.z * w1r[2] + xvA.w * w1r[3];
                float pIB = b1r + xvB.x * w1r[0] + xvB.y * w1r[1] + xvB.z * w1r[2] + xvB.w * w1r[3];
                _Float16 phA = (_Float16)pIA, phB = (_Float16)pIB;
                half2v pIpA = {phA, phA}, pIpB = {phB, phB};
                u32 gmA = gmaskS[i], gmB = gmaskS[iB];
                u32 lowA = (1u << i) - 1u, lowB = (1u << iB) - 1u;
                u32 m2A = __builtin_amdgcn_readfirstlane((gmA & lowA) | ((gmA & ~lowA) << 1));
                u32 m2B = __builtin_amdgcn_readfirstlane((gmB & lowB) | ((gmB & ~lowB) << 1));
                float a0 = 0.f, a1 = 0.f, b0 = 0.f, b1 = 0.f;
#pragma unroll
                for (int m = 0; m < 15; m++) {
                    half2v tA = pIpA + pJp[m];
                    half2v tB = pIpB + pJp[m];
                    tA = __builtin_elementwise_max(tA, zero2);
                    tB = __builtin_elementwise_max(tB, zero2);
#if __has_builtin(__builtin_amdgcn_fdot2)
                    u32 mmA = ((m2A >> (2 * m)) & 1u) * 0x3C00u
                            + ((m2A >> (2 * m + 1)) & 1u) * 0x3C000000u;
                    u32 mmB = ((m2B >> (2 * m)) & 1u) * 0x3C00u
                            + ((m2B >> (2 * m + 1)) & 1u) * 0x3C000000u;
                    half2v mvA = __builtin_bit_cast(half2v, mmA);
                    half2v mvB = __builtin_bit_cast(half2v, mmB);
                    if (m & 1) { a1 = __builtin_amdgcn_fdot2(tA, mvA, a1, false);
                                 b1 = __builtin_amdgcn_fdot2(tB, mvB, b1, false); }
                    else       { a0 = __builtin_amdgcn_fdot2(tA, mvA, a0, false);
                                 b0 = __builtin_amdgcn_fdot2(tB, mvB, b0, false); }
#else
                    u32 mbA = ((m2A >> (2 * m)) & 1u) * 0xFFFFu
                            + ((m2A >> (2 * m + 1)) & 1u) * 0xFFFF0000u;
                    u32 mbB = ((m2B >> (2 * m)) & 1u) * 0xFFFFu
                            + ((m2B >> (2 * m + 1)) & 1u) * 0xFFFF0000u;
                    half2v tvA = __builtin_bit_cast(half2v, __builtin_bit_cast(u32, tA) & mbA);
                    half2v tvB = __builtin_bit_cast(half2v, __builtin_bit_cast(u32, tB) & mbB);
                    a0 += (float)tvA.x; a1 += (float)tvA.y;
                    b0 += (float)tvB.x; b1 += (float)tvB.y;
#endif
                }
                S[set][i  * AST + lane] = f2bf_fast(a0 + a1);
                S[set][iB * AST + lane] = f2bf_fast(b0 + b1);
            }
            // tail row (swv 2,3: one unpaired row)
            if (i < NN) {
                float4 xv = *(const float4*)&xN[set][ci][i * 4];
                float pI = b1r + xv.x * w1r[0] + xv.y * w1r[1] + xv.z * w1r[2] + xv.w * w1r[3];
                _Float16 pih = (_Float16)pI;
                half2v pIp = {pih, pih};
                u32 gm = gmaskS[i];
                u32 lowm = (1u << i) - 1u;
                u32 m2 = __builtin_amdgcn_readfirstlane((gm & lowm) | ((gm & ~lowm) << 1));
                float s0 = 0.f, s1 = 0.f;
#pragma unroll
                for (int m = 0; m < 15; m++) {
                    half2v t = pIp + pJp[m];
                    t = __builtin_elementwise_max(t, zero2);
#if __has_builtin(__builtin_amdgcn_fdot2)
                    u32 mm = ((m2 >> (2 * m)) & 1u) * 0x3C00u
                           + ((m2 >> (2 * m + 1)) & 1u) * 0x3C000000u;
                    half2v mv = __builtin_bit_cast(half2v, mm);
                    if (m & 1) s1 = __builtin_amdgcn_fdot2(t, mv, s1, false);
                    else       s0 = __builtin_amdgcn_fdot2(t, mv, s0, false);
#else
                    u32 mb = ((m2 >> (2 * m)) & 1u) * 0xFFFFu
                           + ((m2 >> (2 * m + 1)) & 1u) * 0xFFFF0000u;
                    u32 tb = __builtin_bit_cast(u32, t) & mb;
                    half2v tv = __builtin_bit_cast(half2v, tb);
                    s0 += (float)tv.x; s1 += (float)tv.y;
#endif
                }
                S[set][i * AST + lane] = f2bf_fast(s0 + s1);
            }
            __syncthreads();

            // ---- S^T B-fragments ----
            short4v Bs[4], Ba[4], Bb[4];
#pragma unroll
            for (int kb = 0; kb < 4; kb++)
                Bs[kb] = *(const short4v*)&S[set][(nb * 16 + ln15) * AST + kb * 16 + quad * 4];

            // ---- register-chained MLP: agg -> h1 -> h2 (no LDS round-trips) ----
            runLayer(lwM2, bAgg, Bs, Ba, ngp, false);   // agg = S@W2 + ng*b2
            runLayer(wH1,  bH1,  Ba, Bb, 1.f, true);    // h1 = relu(agg@W1+b1)
            runLayer(wH2,  bH2,  Bb, Ba, 1.f, true);    // h2 = relu(h1@W2+b2)

            // ---- out layer: D = W3T(reg) @ h2^T ----
            {
                f32x4 acc = {0.f, 0.f, 0.f, 0.f};
#pragma unroll
                for (int kb = 0; kb < 4; kb++) acc = MFMA16(eA[kb], Ba[kb], acc);
                const int n = nb * 16 + ln15;
                const int t = 2 * c + step;
                if (quad == 0 && n < NN) {
                    float v[4];
#pragma unroll
                    for (int r = 0; r < 4; r++) v[r] = acc[r] + b3r[r];
                    if (!isMean) {
#pragma unroll
                        for (int r = 0; r < 4; r++) v[r] = softplus_clip(v[r]);
                    }
                    if (t < 127) {
                        size_t o = (size_t)bs * TSTRIDE + (size_t)t * NF + n * 4
                                 + (isMean ? 0 : OUTHALF);
                        if (isbf) {
                            u16* op = (u16*)out;
                            u32 lo = (u32)f2bf_fast(v[0]) | ((u32)f2bf_fast(v[1]) << 16);
                            u32 hi = (u32)f2bf_fast(v[2]) | ((u32)f2bf_fast(v[3]) << 16);
                            *(u32*)&op[o] = lo;
                            *(u32*)&op[o + 2] = hi;
                        } else {
                            float* op = (float*)out;
                            op[o] = v[0]; op[o+1] = v[1]; op[o+2] = v[2]; op[o+3] = v[3];
                        }
                    }
                    if (isMean && step == 0) {
                        xN[set][ci][n*4]   = v[0]; xN[set][ci][n*4+1] = v[1];
                        xN[set][ci][n*4+2] = v[2]; xN[set][ci][n*4+3] = v[3];
                    }
                }
            }
            __syncthreads();   // xN/S step boundary
        }
    }
}

extern "C" void kernel_launch(void* const* d_in, const int* in_sizes, int n_in,
                              void* d_out, int out_size, void* d_ws, size_t ws_size,
                              hipStream_t stream) {
    (void)in_sizes; (void)n_in; (void)out_size; (void)d_ws; (void)ws_size;

    const void* data  = d_in[0];
    const void* graph = d_in[1];
    const void* mW1 = d_in[2];  const void* mB1 = d_in[3];
    const void* mW2 = d_in[4];  const void* mB2 = d_in[5];
    const void* aW1 = d_in[6];  const void* aB1 = d_in[7];
    const void* aW2 = d_in[8];  const void* aB2 = d_in[9];
    const void* aW3 = d_in[10]; const void* aB3 = d_in[11];
    const void* vW1 = d_in[12]; const void* vB1 = d_in[13];
    const void* vW2 = d_in[14]; const void* vB2 = d_in[15];
    const void* vW3 = d_in[16]; const void* vB3 = d_in[17];

    sim_fused<<<BSZ * BPB, 1024, 0, stream>>>(data, graph,
        mW1, mB1, mW2, mB2,
        aW1, aB1, aW2, aB2, aW3, aB3,
        vW1, vB1, vW2, vB2, vW3, vB3,
        d_out);
}

// Round 16
// 133.405 us; speedup vs baseline: 1.0227x; 1.0227x over previous
//
#include <hip/hip_runtime.h>
#include <hip/hip_bf16.h>
#include <hip/hip_fp16.h>

typedef unsigned short u16;
typedef unsigned int u32;
typedef __attribute__((ext_vector_type(4))) short short4v;  // mfma 16x16x16 A/B frag (2 VGPRs)
typedef __attribute__((ext_vector_type(4))) float f32x4;    // mfma C/D frag
typedef __attribute__((ext_vector_type(2))) _Float16 half2v; // packed fp16 pair

#define NN 30
#define FF 4
#define EE 870
#define BSZ 32
#define CC 64
#define TT 128
#define NF 120
#define TSTRIDE 15240
#define OUTHALF 487680
#define AST 68            // S row stride (u16); 17-dw stride -> 2-way max on frag reads (free)
#define WST 68            // LDS weight row stride (u16)
#define NSETS 4           // channel-sets per block (share one weight copy)
#define NCPB 2            // channels per set (amortize staging; processed SERIALLY)
#define BPB  8            // blocks per bs -> grid 256 = 1 block/CU

// R16 = R12 restored verbatim (session champion: 134.1us total, 53.6us
// dispatch, VGPR 48, zero scratch). Session ledger:
//   R15 row-pair ILP: clean but NEGATIVE (55.5us) -> edge chain depth not
//     the stall. R13 T14 async-stage: neutral -> staging not latency-bound.
//   R9-R11 channel-split: 3x allocator spill -> abandoned.
//   R6 30% VALU cut: neutral -> not VALU-throughput-bound.
// The step loop is a correlated-stall structure (16 barrier-locked waves,
// no saturated pipe: Mfma 9%, VALU 48%, HBM 1%); every within-structure
// lever measured neutral-or-worse. ~80us of the 134 is fixed harness
// residue. This structure is at its practical floor.

__device__ __forceinline__ float bf2f(u16 u) {
    union { u32 i; float f; } v; v.i = ((u32)u) << 16; return v.f;
}
// fast RNE f32->bf16 (finite values): ~4 VALU instead of libcall sequence
__device__ __forceinline__ u16 f2bf_fast(float f) {
    union { float f; u32 u; } v; v.f = f;
    return (u16)((v.u + 0x7FFFu + ((v.u >> 16) & 1u)) >> 16);
}
__device__ __forceinline__ float ldv(const void* p, int idx, int isbf) {
    if (isbf) return bf2f(((const u16*)p)[idx]);
    return ((const float*)p)[idx];
}
// fast softplus+clip: v_exp/v_log based. Matches exact path at both clip
// boundaries (large +z: log(1+0)=0; very -z: underflows to 0 then clips to 1e-8).
__device__ __forceinline__ float softplus_clip(float z) {
    float t = __expf(-fabsf(z));
    float sp = fmaxf(z, 0.f) + __logf(1.f + t);
    return fminf(fmaxf(sp, 1e-8f), 100.f);
}
__device__ __forceinline__ f32x4 MFMA16(short4v a, short4v b, f32x4 c) {
    return __builtin_amdgcn_mfma_f32_16x16x16bf16_1k(a, b, c, 0, 0, 0);
}

__device__ __forceinline__ int probe_isbf(const u16* g, int lane) {
    int hit = (g[2 * lane] == 0x3F80u) | (g[128 + 2 * lane] == 0x3F80u);
    unsigned long long b = __ballot(hit);
    return (b != 0ull) ? 1 : 0;
}

// LDS = 43520(W) + 4*4352(S) + 8*480(xN) + 128 gmask + 1280 bias = 66176 B.
// launch_bounds(1024, 4): VGPR cap 128; compiles ~48 VGPR (8 waves/SIMD ok).
// NOTE: (1024, 8) regressed badly: 64-VGPR cap forced scratch spill. Keep 4.
__global__ __launch_bounds__(1024, 4)
void sim_fused(const void* __restrict__ data,
               const void* __restrict__ graph,
               const void* __restrict__ mW1, const void* __restrict__ mB1,
               const void* __restrict__ mW2, const void* __restrict__ mB2,
               const void* __restrict__ aW1, const void* __restrict__ aB1,
               const void* __restrict__ aW2, const void* __restrict__ aB2,
               const void* __restrict__ aW3, const void* __restrict__ aB3,
               const void* __restrict__ vW1, const void* __restrict__ vB1,
               const void* __restrict__ vW2, const void* __restrict__ vB2,
               const void* __restrict__ vW3, const void* __restrict__ vB3,
               void* __restrict__ out)
{
    __shared__ __align__(16) float xN[NSETS][NCPB][NF];
    __shared__ __align__(16) u32 gmaskS[32];
    __shared__ __align__(16) u16 S[NSETS][32 * AST];
    __shared__ __align__(16) u16 lwM2[64 * WST];
    __shared__ __align__(16) u16 lwH1m[64 * WST];
    __shared__ __align__(16) u16 lwH2m[64 * WST];
    __shared__ __align__(16) u16 lwH1v[64 * WST];
    __shared__ __align__(16) u16 lwH2v[64 * WST];
    __shared__ __align__(16) float biasL[5 * 64];  // mB2|aB1|aB2|vB1|vB2

    const int tid  = threadIdx.x;
    const int lane = tid & 63;
    const int wv   = tid >> 6;        // 0..15
    const int set  = wv >> 2;         // 0..3 : channel-set
    const int swv  = wv & 3;          // 0..3 within set
    const int ln15 = lane & 15;
    const int quad = lane >> 4;
    const int bs   = blockIdx.x / BPB;
    const int bg   = blockIdx.x % BPB;
    const int cg   = bg * NSETS + set; // channel group 0..31 (NCPB channels each)
    const int isbf = probe_isbf((const u16*)graph, lane);

    const bool isMean = (swv < 2);
    const int nb = swv & 1;           // this wave's 16-node block

    // ---- phase 0: zero gmask + S pad rows ----
    if (tid < 32) gmaskS[tid] = 0u;
    if (tid < 512) {  // zero pad rows 30,31 of all 4 sets' S (stay zero forever)
        int s2 = tid >> 7, row = 30 + ((tid >> 6) & 1);
        S[s2][row * AST + (tid & 63)] = 0;
    }
    __syncthreads();   // gmask zeroing visible before atomics

    // ---- phase 1: one-time staging (masks, weights transposed, biases, xN) ----
    if (tid < EE) {    // coalesced: graph row for this bs is contiguous
        int i = tid / 29;
        int e = tid - i * 29;
        if (ldv(graph, bs * EE + tid, isbf) > 0.5f)
            atomicOr(&gmaskS[i], 1u << e);
    }
    // transpose five 64x64 weights into LDS o-major rows (stride WST).
    if (isbf) {
        // bf16 source: u32 loads (2 o's per load), raw u16 writes
        // (f2bf(bf2f(x)) is identity -> numerics unchanged vs scalar path)
        for (int idx2 = tid; idx2 < 2048; idx2 += 1024) {  // 2 iters x 5 arrays
            int k = idx2 >> 5, o = (idx2 & 31) * 2;
            int d0 = o * WST + k, d1 = d0 + WST;
            u32 w;
            w = ((const u32*)mW2)[idx2]; lwM2[d0]  = (u16)w; lwM2[d1]  = (u16)(w >> 16);
            w = ((const u32*)aW1)[idx2]; lwH1m[d0] = (u16)w; lwH1m[d1] = (u16)(w >> 16);
            w = ((const u32*)aW2)[idx2]; lwH2m[d0] = (u16)w; lwH2m[d1] = (u16)(w >> 16);
            w = ((const u32*)vW1)[idx2]; lwH1v[d0] = (u16)w; lwH1v[d1] = (u16)(w >> 16);
            w = ((const u32*)vW2)[idx2]; lwH2v[d0] = (u16)w; lwH2v[d1] = (u16)(w >> 16);
        }
    } else {
        for (int idx = tid; idx < 4096; idx += 1024) {  // 4 iters x 5 arrays
            int k = idx >> 6, o = idx & 63;
            int d = o * WST + k;
            lwM2[d]  = f2bf_fast(((const float*)mW2)[idx]);
            lwH1m[d] = f2bf_fast(((const float*)aW1)[idx]);
            lwH2m[d] = f2bf_fast(((const float*)aW2)[idx]);
            lwH1v[d] = f2bf_fast(((const float*)vW1)[idx]);
            lwH2v[d] = f2bf_fast(((const float*)vW2)[idx]);
        }
    }
    if (tid < 64) {
        biasL[tid]       = ldv(mB2, tid, isbf);
        biasL[64 + tid]  = ldv(aB1, tid, isbf);
        biasL[128 + tid] = ldv(aB2, tid, isbf);
        biasL[192 + tid] = ldv(vB1, tid, isbf);
        biasL[256 + tid] = ldv(vB2, tid, isbf);
    }
    // stage BOTH channels' features for this set (upfront: saves 2 barriers)
    {
        const int setTid = tid & 255;
#pragma unroll
        for (int cj = 0; cj < NCPB; cj++) {
            const int cc = cg * NCPB + cj;
            if (isbf) {
                if (setTid < 60) {
                    u32 w = ((const u32*)data)[((bs * TT + 2 * cc) * NF) / 2 + setTid];
                    xN[set][cj][setTid * 2]     = bf2f((u16)(w & 0xFFFF));
                    xN[set][cj][setTid * 2 + 1] = bf2f((u16)(w >> 16));
                }
            } else {
                if (setTid < NF)
                    xN[set][cj][setTid] = ((const float*)data)[(bs * TT + 2 * cc) * NF + setTid];
            }
        }
    }

    // ---- register-resident constants (no LDS dependency) ----
    float w1r[8];
#pragma unroll
    for (int k = 0; k < 8; k++) w1r[k] = ldv(mW1, k * 64 + lane, isbf);
    const float b1r = ldv(mB1, lane, isbf);
    float b3r[4];
#pragma unroll
    for (int r = 0; r < 4; r++) b3r[r] = ldv(isMean ? aB3 : vB3, r, isbf);

    const u16* wH1 = isMean ? lwH1m : lwH1v;
    const u16* wH2 = isMean ? lwH2m : lwH2v;
    const float* bAgg = biasL;
    const float* bH1  = isMean ? (biasL + 64)  : (biasL + 192);
    const float* bH2  = isMean ? (biasL + 128) : (biasL + 256);

    // W3^T A-fragments in registers (16x64 padded; rows>=4 zero)
    const void* W3src = isMean ? aW3 : vW3;
    short4v eA[4];
#pragma unroll
    for (int kb = 0; kb < 4; kb++) {
        union { short4v v; u16 s[4]; } pk;
#pragma unroll
        for (int j = 0; j < 4; j++) {
            int k = kb * 16 + quad * 4 + j;
            pk.s[j] = (ln15 < 4)
                ? (isbf ? ((const u16*)W3src)[k * 4 + ln15]
                        : f2bf_fast(((const float*)W3src)[k * 4 + ln15]))
                : (u16)0;
        }
        eA[kb] = pk.v;
    }

    __syncthreads();   // one-time staging visible

    const int myNode = nb * 16 + ln15;
    const float ngp = (myNode < NN) ? (float)__popc(gmaskS[myNode]) : 0.f;

    // transposed-chain layer: register B-frag in, register B-frag out
    auto runLayer = [&](const u16* wl, const float* bl, const short4v* Bin,
                        short4v* Bout, float bscale, bool doRelu) {
#pragma unroll
        for (int fb = 0; fb < 4; fb++) {
            f32x4 acc = {0.f, 0.f, 0.f, 0.f};
#pragma unroll
            for (int kb = 0; kb < 4; kb++) {
                short4v a = *(const short4v*)&wl[(fb * 16 + ln15) * WST + kb * 16 + quad * 4];
                acc = MFMA16(a, Bin[kb], acc);
            }
            float4 bv = *(const float4*)&bl[fb * 16 + quad * 4];
            union { short4v v; u16 s[4]; } pk;
#pragma unroll
            for (int r = 0; r < 4; r++) {
                float val = acc[r] + bscale * (&bv.x)[r];
                if (doRelu) val = fmaxf(val, 0.f);
                pk.s[r] = f2bf_fast(val);
            }
            Bout[fb] = pk.v;
        }
    };

    const half2v zero2 = {(_Float16)0.f, (_Float16)0.f};

    for (int ci = 0; ci < NCPB; ci++) {
        const int c = cg * NCPB + ci;

        for (int step = 0; step < 2; step++) {
            // ---- pJ pairs in registers (per-wave redundant; no LDS, no barrier) ----
            // pJp[m] = fp16x2 { x_{2m}.W1[4:8,lane], x_{2m+1}.W1[4:8,lane] }, RNE
            half2v pJp[15];
#pragma unroll
            for (int m = 0; m < 15; m++) {
                float4 xa = *(const float4*)&xN[set][ci][(2 * m) * 4];
                float4 xb = *(const float4*)&xN[set][ci][(2 * m + 1) * 4];
                half2v p;
                p.x = (_Float16)(xa.x * w1r[4] + xa.y * w1r[5] + xa.z * w1r[6] + xa.w * w1r[7]);
                p.y = (_Float16)(xb.x * w1r[4] + xb.y * w1r[5] + xb.z * w1r[6] + xb.w * w1r[7]);
                pJp[m] = p;
            }

            // ---- edge accumulation (branchless, packed fp16, masks built in SALU) ----
            // S[i][h] = sum_j mask_ij * relu(pI_i + pJ_j)
            for (int i = swv; i < NN; i += 4) {
                float4 xv = *(const float4*)&xN[set][ci][i * 4];
                float pI = b1r + xv.x * w1r[0] + xv.y * w1r[1] + xv.z * w1r[2] + xv.w * w1r[3];
                _Float16 pih = (_Float16)pI;
                half2v pIp = {pih, pih};
                u32 gm = gmaskS[i];
                // remap edge-bit e -> node j (j = e + (e>=i)): bit i becomes 0
                u32 lowm = (1u << i) - 1u;
                u32 m2 = __builtin_amdgcn_readfirstlane((gm & lowm) | ((gm & ~lowm) << 1));
                float s0 = 0.f, s1 = 0.f;
#pragma unroll
                for (int m = 0; m < 15; m++) {
                    half2v t = pIp + pJp[m];                       // v_pk_add_f16
                    t = __builtin_elementwise_max(t, zero2);       // v_pk_max_f16 (relu)
#if __has_builtin(__builtin_amdgcn_fdot2)
                    // fp16 {1.0, 0.0} mask pair, built on the scalar pipe (m2 uniform)
                    u32 mm = ((m2 >> (2 * m)) & 1u) * 0x3C00u
                           + ((m2 >> (2 * m + 1)) & 1u) * 0x3C000000u;
                    half2v mv = __builtin_bit_cast(half2v, mm);
                    if (m & 1) s1 = __builtin_amdgcn_fdot2(t, mv, s1, false);
                    else       s0 = __builtin_amdgcn_fdot2(t, mv, s0, false);
#else
                    // fallback: full-half bitmask AND, then widen-accumulate
                    u32 mb = ((m2 >> (2 * m)) & 1u) * 0xFFFFu
                           + ((m2 >> (2 * m + 1)) & 1u) * 0xFFFF0000u;
                    u32 tb = __builtin_bit_cast(u32, t) & mb;
                    half2v tv = __builtin_bit_cast(half2v, tb);
                    s0 += (float)tv.x; s1 += (float)tv.y;
#endif
                }
                S[set][i * AST + lane] = f2bf_fast(s0 + s1);
            }
            __syncthreads();

            // ---- S^T B-fragments ----
            short4v Bs[4], Ba[4], Bb[4];
#pragma unroll
            for (int kb = 0; kb < 4; kb++)
                Bs[kb] = *(const short4v*)&S[set][(nb * 16 + ln15) * AST + kb * 16 + quad * 4];

            // ---- register-chained MLP: agg -> h1 -> h2 (no LDS round-trips) ----
            runLayer(lwM2, bAgg, Bs, Ba, ngp, false);   // agg = S@W2 + ng*b2
            runLayer(wH1,  bH1,  Ba, Bb, 1.f, true);    // h1 = relu(agg@W1+b1)
            runLayer(wH2,  bH2,  Bb, Ba, 1.f, true);    // h2 = relu(h1@W2+b2)

            // ---- out layer: D = W3T(reg) @ h2^T ----
            {
                f32x4 acc = {0.f, 0.f, 0.f, 0.f};
#pragma unroll
                for (int kb = 0; kb < 4; kb++) acc = MFMA16(eA[kb], Ba[kb], acc);
                const int n = nb * 16 + ln15;
                const int t = 2 * c + step;
                if (quad == 0 && n < NN) {
                    float v[4];
#pragma unroll
                    for (int r = 0; r < 4; r++) v[r] = acc[r] + b3r[r];
                    if (!isMean) {
#pragma unroll
                        for (int r = 0; r < 4; r++) v[r] = softplus_clip(v[r]);
                    }
                    if (t < 127) {
                        size_t o = (size_t)bs * TSTRIDE + (size_t)t * NF + n * 4
                                 + (isMean ? 0 : OUTHALF);
                        if (isbf) {
                            u16* op = (u16*)out;
                            u32 lo = (u32)f2bf_fast(v[0]) | ((u32)f2bf_fast(v[1]) << 16);
                            u32 hi = (u32)f2bf_fast(v[2]) | ((u32)f2bf_fast(v[3]) << 16);
                            *(u32*)&op[o] = lo;
                            *(u32*)&op[o + 2] = hi;
                        } else {
                            float* op = (float*)out;
                            op[o] = v[0]; op[o+1] = v[1]; op[o+2] = v[2]; op[o+3] = v[3];
                        }
                    }
                    if (isMean && step == 0) {
                        xN[set][ci][n*4]   = v[0]; xN[set][ci][n*4+1] = v[1];
                        xN[set][ci][n*4+2] = v[2]; xN[set][ci][n*4+3] = v[3];
                    }
                }
            }
            __syncthreads();   // xN/S step boundary
        }
    }
}

extern "C" void kernel_launch(void* const* d_in, const int* in_sizes, int n_in,
                              void* d_out, int out_size, void* d_ws, size_t ws_size,
                              hipStream_t stream) {
    (void)in_sizes; (void)n_in; (void)out_size; (void)d_ws; (void)ws_size;

    const void* data  = d_in[0];
    const void* graph = d_in[1];
    const void* mW1 = d_in[2];  const void* mB1 = d_in[3];
    const void* mW2 = d_in[4];  const void* mB2 = d_in[5];
    const void* aW1 = d_in[6];  const void* aB1 = d_in[7];
    const void* aW2 = d_in[8];  const void* aB2 = d_in[9];
    const void* aW3 = d_in[10]; const void* aB3 = d_in[11];
    const void* vW1 = d_in[12]; const void* vB1 = d_in[13];
    const void* vW2 = d_in[14]; const void* vB2 = d_in[15];
    const void* vW3 = d_in[16]; const void* vB3 = d_in[17];

    sim_fused<<<BSZ * BPB, 1024, 0, stream>>>(data, graph,
        mW1, mB1, mW2, mB2,
        aW1, aB1, aW2, aB2, aW3, aB3,
        vW1, vB1, vW2, vB2, vW3, vB3,
        d_out);
}